// Round 3
// baseline (662.095 us; speedup 1.0000x reference)
//
#include <hip/hip_runtime.h>
#include <math.h>

typedef short bf16x8 __attribute__((ext_vector_type(8)));
typedef float f32x16 __attribute__((ext_vector_type(16)));
typedef unsigned short u16;
typedef unsigned int u32;

constexpr int LMAX = 8;

__device__ __forceinline__ u16 f2bf(float x) {
    u32 u = __float_as_uint(x);
    u += 0x7FFFu + ((u >> 16) & 1u);
    return (u16)(u >> 16);
}

__device__ __forceinline__ u32 cvt_pk_bf16(float lo, float hi) {
    u32 r;
    asm("v_cvt_pk_bf16_f32 %0, %1, %2" : "=v"(r) : "v"(lo), "v"(hi));
    return r;
}

__device__ __forceinline__ void pl32_swap(u32 &x, u32 &y) {
    asm volatile("v_permlane32_swap_b32 %0, %1" : "+v"(x), "+v"(y));
}

__device__ __forceinline__ bf16x8 frag_from(u32 a, u32 b, u32 c, u32 d) {
    union { u32 u[4]; bf16x8 v; } t;
    t.u[0] = a; t.u[1] = b; t.u[2] = c; t.u[3] = d;
    return t.v;
}

// ---------------- weight prepack ----------------
// ws (u16): [0:12288) A1 frags (24 blocks), [12288:36864) W2 frags (48 blocks)
// A1 blk<18: rot tile nt=blk/3, kstep=blk%3; A[row=l31 of tile nt][k=16*kstep+8*hi+j]
//   k<32 -> Wr1[k][h]; k==32 -> br1[h] (bias via X col 32 = 1.0); else 0
// A1 blk 18..23: scalar tile; k=32+8hi+j: k==32 -> bs1[h]; 33..36 -> Ws1[k-33][h]; else 0
// W2 blk = mlp*24 + ks*2 + nto: B[k=16ks+8hi+j][col=nto*32+l31]
__global__ void prepack_kernel(const float* __restrict__ Ws1, const float* __restrict__ bs1,
                               const float* __restrict__ Ws2, const float* __restrict__ Wr1,
                               const float* __restrict__ br1, const float* __restrict__ Wr2,
                               u16* __restrict__ ws)
{
    int idx = blockIdx.x * blockDim.x + threadIdx.x;
    if (idx >= 36864) return;
    int e = idx & 511, l = e >> 3, j = e & 7, hi = l >> 5, l31 = l & 31;
    float val = 0.0f;
    if (idx < 12288) {
        int blk = idx >> 9;
        if (blk < 18) {
            int nt = blk / 3, kstep = blk % 3;
            int h = nt * 32 + l31;
            int k = kstep * 16 + 8 * hi + j;
            val = (k < 32) ? Wr1[k * 192 + h] : ((k == 32) ? br1[h] : 0.0f);
        } else {
            int h = (blk - 18) * 32 + l31;
            int k = 32 + 8 * hi + j;
            val = (k == 32) ? bs1[h] : ((k >= 33 && k <= 36) ? Ws1[(k - 33) * 192 + h] : 0.0f);
        }
    } else {
        int t = idx - 12288;
        int blk = t >> 9;
        int mlp = blk / 24, rem = blk % 24, ks = rem >> 1, nto = rem & 1;
        int k = 16 * ks + 8 * hi + j;
        int col = nto * 32 + l31;
        val = (mlp == 0 ? Wr2 : Ws2)[k * 64 + col];
    }
    ws[idx] = f2bf(val);
}

// ---------------- main fused kernel: 1 wave = 64 nodes ----------------
__global__ __launch_bounds__(256, 3) void node_embed_mfma(
    const float* __restrict__ v, const float* __restrict__ force,
    const int* __restrict__ is_moving, const float* __restrict__ rot_theta,
    const float* __restrict__ br2, const float* __restrict__ bs2,
    const u16* __restrict__ wpack,
    float* __restrict__ out, int n)
{
    __shared__ u16 Xs[4][64 * 40];   // per-wave X tile: 64 rows x 40 cols

    const int lane = threadIdx.x & 63;
    const int w    = threadIdx.x >> 6;
    const int hi   = lane >> 5;
    const int l31  = lane & 31;
    const int nodeBase = blockIdx.x * 256 + w * 64;

    // ---- featurization: lane = node ----
    const int node = nodeBase + lane;
    const int ldn  = min(node, n - 1);

    const float2 f2 = *reinterpret_cast<const float2*>(force + (size_t)ldn * 2);
    const float2 v2 = *reinterpret_cast<const float2*>(v     + (size_t)ldn * 2);
    const float fn = sqrtf(f2.x * f2.x + f2.y * f2.y);
    const float vn = sqrtf(v2.x * v2.x + v2.y * v2.y);
    const float cf = f2.x / fn, sf = f2.y / fn;
    const float cv = v2.x / vn, sv = v2.y / vn;
    const int mov = is_moving[ldn];

    float rotf[2 * LMAX], rotv[2 * LMAX];
    rotf[0] = cf; rotf[1] = sf;
    rotv[0] = cv; rotv[1] = sv;
    #pragma unroll
    for (int k = 1; k < LMAX; ++k) {
        rotf[2*k]   = rotf[2*k-2] * cf - rotf[2*k-1] * sf;
        rotf[2*k+1] = rotf[2*k-1] * cf + rotf[2*k-2] * sf;
        rotv[2*k]   = rotv[2*k-2] * cv - rotv[2*k-1] * sv;
        rotv[2*k+1] = rotv[2*k-1] * cv + rotv[2*k-2] * sv;
    }

    const float* Rbase = rot_theta + (size_t)ldn * 32;
    u16 xv[40];
    #pragma unroll
    for (int k = 0; k < LMAX; ++k) {
        const float4 R = *reinterpret_cast<const float4*>(Rbase + k * 4);
        {
            const float a = rotf[2*k], b = rotf[2*k+1];
            xv[2*k + 0] = f2bf(fmaf(R.x, a, R.y * b));
            xv[2*k + 1] = f2bf(fmaf(R.z, a, R.w * b));
        }
        {
            const float a = rotv[2*k], b = rotv[2*k+1];
            xv[16 + 2*k + 0] = f2bf(fmaf(R.x, a, R.y * b));
            xv[16 + 2*k + 1] = f2bf(fmaf(R.z, a, R.w * b));
        }
    }
    // cols 32..39: [1.0(bias), fn, vn, oh0, oh1, 0, 0, 0]
    xv[32] = 0x3F80;
    xv[33] = f2bf(fn);
    xv[34] = f2bf(vn);
    xv[35] = (mov == 0) ? 0x3F80 : 0;
    xv[36] = (mov == 1) ? 0x3F80 : 0;
    xv[37] = 0; xv[38] = 0; xv[39] = 0;

    {
        u32 xu[20];
        #pragma unroll
        for (int i = 0; i < 20; ++i)
            xu[i] = (u32)xv[2*i] | ((u32)xv[2*i+1] << 16);
        uint4* xdst = reinterpret_cast<uint4*>(&Xs[w][lane * 40]);
        #pragma unroll
        for (int i = 0; i < 5; ++i)
            xdst[i] = make_uint4(xu[4*i], xu[4*i+1], xu[4*i+2], xu[4*i+3]);
    }

    // per-lane output biases (col = nto*32 + l31)
    const float b2r0 = br2[l31], b2r1 = br2[32 + l31];
    const float b2s0 = bs2[l31], b2s1 = bs2[32 + l31];

    const u16* A1 = wpack;
    const u16* W2 = wpack + 12288;

    const int kk  = (l31 & 15) >> 1;
    const bool oddl = (l31 & 1) != 0;

    for (int mg = 0; mg < 2; ++mg) {
        const int rowA = mg * 32 + l31;
        const bf16x8 xb0 = *reinterpret_cast<const bf16x8*>(&Xs[w][rowA * 40 + 8 * hi]);
        const bf16x8 xb1 = *reinterpret_cast<const bf16x8*>(&Xs[w][rowA * 40 + 16 + 8 * hi]);
        const bf16x8 xq4 = *reinterpret_cast<const bf16x8*>(&Xs[w][rowA * 40 + 32]);

        // ===== rot MLP =====
        f32x16 acc0, acc1;
        #pragma unroll
        for (int r = 0; r < 16; ++r) { acc0[r] = b2r0; acc1[r] = b2r1; }

        #pragma unroll
        for (int a = 0; a < 6; ++a) {
            f32x16 d1;
            #pragma unroll
            for (int r = 0; r < 16; ++r) d1[r] = 0.0f;
            d1 = __builtin_amdgcn_mfma_f32_32x32x16_bf16(
                *reinterpret_cast<const bf16x8*>(&A1[(a*3+0)*512 + lane*8]), xb0, d1, 0, 0, 0);
            d1 = __builtin_amdgcn_mfma_f32_32x32x16_bf16(
                *reinterpret_cast<const bf16x8*>(&A1[(a*3+1)*512 + lane*8]), xb1, d1, 0, 0, 0);
            d1 = __builtin_amdgcn_mfma_f32_32x32x16_bf16(
                *reinterpret_cast<const bf16x8*>(&A1[(a*3+2)*512 + lane*8]), xq4, d1, 0, 0, 0);

            u32 q[8];
            #pragma unroll
            for (int m = 0; m < 8; ++m)
                q[m] = cvt_pk_bf16(fmaxf(d1[2*m], 0.0f), fmaxf(d1[2*m+1], 0.0f));

            #pragma unroll
            for (int b = 0; b < 2; ++b) {
                u32 p0 = q[4*b + 0], p2 = q[4*b + 2];
                u32 p1 = q[4*b + 1], p3 = q[4*b + 3];
                pl32_swap(p0, p2);
                pl32_swap(p1, p3);
                const bf16x8 af = frag_from(p0, p1, p2, p3);
                const int ks = 2*a + b;
                acc0 = __builtin_amdgcn_mfma_f32_32x32x16_bf16(
                    af, *reinterpret_cast<const bf16x8*>(&W2[(ks*2+0)*512 + lane*8]), acc0, 0, 0, 0);
                acc1 = __builtin_amdgcn_mfma_f32_32x32x16_bf16(
                    af, *reinterpret_cast<const bf16x8*>(&W2[(ks*2+1)*512 + lane*8]), acc1, 0, 0, 0);
            }
        }

        // epilogue rot: output rotation + store
        #pragma unroll
        for (int rq = 0; rq < 4; ++rq) {
            #pragma unroll
            for (int rr = 0; rr < 4; ++rr) {
                const int r  = rq * 4 + rr;
                const int nd = nodeBase + mg * 32 + rr + 8 * rq + 4 * hi;
                const int ln = min(nd, n - 1);
                const float4 R = *reinterpret_cast<const float4*>(rot_theta + (size_t)ln * 32 + kk * 4);
                const float a0 = acc0[r], a1 = acc1[r];
                const float p0 = __shfl_xor(a0, 1, 64);
                const float p1 = __shfl_xor(a1, 1, 64);
                const float r0 = oddl ? fmaf(p0, R.y, a0 * R.w) : fmaf(a0, R.x, p0 * R.z);
                const float r1 = oddl ? fmaf(p1, R.y, a1 * R.w) : fmaf(a1, R.x, p1 * R.z);
                if (nd < n) {
                    float* orow = out + (size_t)n * 64 + (size_t)nd * 64;
                    orow[l31]      = r0;
                    orow[32 + l31] = r1;
                }
            }
        }

        // ===== scalar MLP =====
        #pragma unroll
        for (int r = 0; r < 16; ++r) { acc0[r] = b2s0; acc1[r] = b2s1; }

        #pragma unroll
        for (int a = 0; a < 6; ++a) {
            f32x16 d1;
            #pragma unroll
            for (int r = 0; r < 16; ++r) d1[r] = 0.0f;
            d1 = __builtin_amdgcn_mfma_f32_32x32x16_bf16(
                *reinterpret_cast<const bf16x8*>(&A1[(18 + a)*512 + lane*8]), xq4, d1, 0, 0, 0);

            u32 q[8];
            #pragma unroll
            for (int m = 0; m < 8; ++m)
                q[m] = cvt_pk_bf16(fmaxf(d1[2*m], 0.0f), fmaxf(d1[2*m+1], 0.0f));

            #pragma unroll
            for (int b = 0; b < 2; ++b) {
                u32 p0 = q[4*b + 0], p2 = q[4*b + 2];
                u32 p1 = q[4*b + 1], p3 = q[4*b + 3];
                pl32_swap(p0, p2);
                pl32_swap(p1, p3);
                const bf16x8 af = frag_from(p0, p1, p2, p3);
                const int ks = 2*a + b;
                acc0 = __builtin_amdgcn_mfma_f32_32x32x16_bf16(
                    af, *reinterpret_cast<const bf16x8*>(&W2[(24 + ks*2+0)*512 + lane*8]), acc0, 0, 0, 0);
                acc1 = __builtin_amdgcn_mfma_f32_32x32x16_bf16(
                    af, *reinterpret_cast<const bf16x8*>(&W2[(24 + ks*2+1)*512 + lane*8]), acc1, 0, 0, 0);
            }
        }

        // epilogue scalar: direct store
        #pragma unroll
        for (int rq = 0; rq < 4; ++rq) {
            #pragma unroll
            for (int rr = 0; rr < 4; ++rr) {
                const int r  = rq * 4 + rr;
                const int nd = nodeBase + mg * 32 + rr + 8 * rq + 4 * hi;
                if (nd < n) {
                    float* orow = out + (size_t)nd * 64;
                    orow[l31]      = acc0[r];
                    orow[32 + l31] = acc1[r];
                }
            }
        }
    }
}

// ---------------- fallback (VALU) if ws too small ----------------
__global__ __launch_bounds__(256) void node_embed_valu(
    const float* __restrict__ v, const float* __restrict__ force,
    const int* __restrict__ is_moving, const float* __restrict__ rot_theta,
    const float* __restrict__ Ws1, const float* __restrict__ bs1,
    const float* __restrict__ Ws2, const float* __restrict__ bs2,
    const float* __restrict__ Wr1, const float* __restrict__ br1,
    const float* __restrict__ Wr2, const float* __restrict__ br2,
    float* __restrict__ out, int n)
{
    const int node = blockIdx.x * blockDim.x + threadIdx.x;
    if (node >= n) return;
    const float2 f2 = *reinterpret_cast<const float2*>(force + (size_t)node * 2);
    const float2 v2 = *reinterpret_cast<const float2*>(v     + (size_t)node * 2);
    const float fn = sqrtf(f2.x * f2.x + f2.y * f2.y);
    const float vn = sqrtf(v2.x * v2.x + v2.y * v2.y);
    const float cf = f2.x / fn, sf = f2.y / fn;
    const float cv = v2.x / vn, sv = v2.y / vn;
    const int mov = is_moving[node];
    float rotf[16], rotv[16];
    rotf[0] = cf; rotf[1] = sf; rotv[0] = cv; rotv[1] = sv;
    #pragma unroll
    for (int k = 1; k < 8; ++k) {
        rotf[2*k]   = rotf[2*k-2] * cf - rotf[2*k-1] * sf;
        rotf[2*k+1] = rotf[2*k-1] * cf + rotf[2*k-2] * sf;
        rotv[2*k]   = rotv[2*k-2] * cv - rotv[2*k-1] * sv;
        rotv[2*k+1] = rotv[2*k-1] * cv + rotv[2*k-2] * sv;
    }
    const float* Rb = rot_theta + (size_t)node * 32;
    float x_in[32];
    #pragma unroll
    for (int k = 0; k < 8; ++k) {
        const float4 R = *reinterpret_cast<const float4*>(Rb + k * 4);
        { const float a = rotf[2*k], b = rotf[2*k+1];
          x_in[2*k] = fmaf(R.x,a,R.y*b); x_in[2*k+1] = fmaf(R.z,a,R.w*b); }
        { const float a = rotv[2*k], b = rotv[2*k+1];
          x_in[16+2*k] = fmaf(R.x,a,R.y*b); x_in[16+2*k+1] = fmaf(R.z,a,R.w*b); }
    }
    float acc[64];
    #pragma unroll
    for (int j = 0; j < 64; ++j) acc[j] = br2[j];
    for (int h = 0; h < 192; h += 4) {
        float hid[4];
        #pragma unroll
        for (int u = 0; u < 4; ++u) {
            float t = br1[h+u];
            #pragma unroll
            for (int i = 0; i < 32; ++i) t = fmaf(x_in[i], Wr1[i*192+h+u], t);
            hid[u] = fmaxf(t, 0.0f);
        }
        #pragma unroll
        for (int j = 0; j < 64; ++j) {
            float t = acc[j];
            #pragma unroll
            for (int u = 0; u < 4; ++u) t = fmaf(hid[u], Wr2[(h+u)*64+j], t);
            acc[j] = t;
        }
    }
    #pragma unroll
    for (int k = 0; k < 8; ++k) {
        const float4 R = *reinterpret_cast<const float4*>(Rb + k * 4);
        #pragma unroll
        for (int j = 0; j < 4; ++j) {
            const int p = j*16 + 2*k;
            const float a = acc[p], b = acc[p+1];
            acc[p] = fmaf(a,R.x,b*R.z); acc[p+1] = fmaf(a,R.y,b*R.w);
        }
    }
    float* orow = out + (size_t)n * 64 + (size_t)node * 64;
    #pragma unroll
    for (int j = 0; j < 16; ++j)
        *reinterpret_cast<float4*>(orow + 4*j) =
            make_float4(acc[4*j], acc[4*j+1], acc[4*j+2], acc[4*j+3]);
    const float s0 = fn, s1 = vn, s2 = (mov==0)?1.f:0.f, s3 = (mov==1)?1.f:0.f;
    #pragma unroll
    for (int j = 0; j < 64; ++j) acc[j] = bs2[j];
    for (int h = 0; h < 192; h += 4) {
        float hid[4];
        #pragma unroll
        for (int u = 0; u < 4; ++u) {
            float t = bs1[h+u];
            t = fmaf(s0, Ws1[0*192+h+u], t); t = fmaf(s1, Ws1[1*192+h+u], t);
            t = fmaf(s2, Ws1[2*192+h+u], t); t = fmaf(s3, Ws1[3*192+h+u], t);
            hid[u] = fmaxf(t, 0.0f);
        }
        #pragma unroll
        for (int j = 0; j < 64; ++j) {
            float t = acc[j];
            #pragma unroll
            for (int u = 0; u < 4; ++u) t = fmaf(hid[u], Ws2[(h+u)*64+j], t);
            acc[j] = t;
        }
    }
    orow = out + (size_t)node * 64;
    #pragma unroll
    for (int j = 0; j < 16; ++j)
        *reinterpret_cast<float4*>(orow + 4*j) =
            make_float4(acc[4*j], acc[4*j+1], acc[4*j+2], acc[4*j+3]);
}

extern "C" void kernel_launch(void* const* d_in, const int* in_sizes, int n_in,
                              void* d_out, int out_size, void* d_ws, size_t ws_size,
                              hipStream_t stream) {
    const int n = in_sizes[0] / 2;
    if (ws_size >= 36864 * sizeof(u16)) {
        hipLaunchKernelGGL(prepack_kernel, dim3(144), dim3(256), 0, stream,
                           (const float*)d_in[4],   // Ws1
                           (const float*)d_in[5],   // bs1
                           (const float*)d_in[6],   // Ws2
                           (const float*)d_in[8],   // Wr1
                           (const float*)d_in[9],   // br1
                           (const float*)d_in[10],  // Wr2
                           (u16*)d_ws);
        hipLaunchKernelGGL(node_embed_mfma, dim3((n + 255) / 256), dim3(256), 0, stream,
                           (const float*)d_in[0], (const float*)d_in[1],
                           (const int*)d_in[2],   (const float*)d_in[3],
                           (const float*)d_in[11],  // br2
                           (const float*)d_in[7],   // bs2
                           (const u16*)d_ws, (float*)d_out, n);
    } else {
        hipLaunchKernelGGL(node_embed_valu, dim3((n + 255) / 256), dim3(256), 0, stream,
                           (const float*)d_in[0], (const float*)d_in[1],
                           (const int*)d_in[2],   (const float*)d_in[3],
                           (const float*)d_in[4], (const float*)d_in[5],
                           (const float*)d_in[6], (const float*)d_in[7],
                           (const float*)d_in[8], (const float*)d_in[9],
                           (const float*)d_in[10],(const float*)d_in[11],
                           (float*)d_out, n);
    }
}

// Round 4
// 513.728 us; speedup vs baseline: 1.2888x; 1.2888x over previous
//
#include <hip/hip_runtime.h>
#include <math.h>

typedef short bf16x8 __attribute__((ext_vector_type(8)));
typedef float f32x16 __attribute__((ext_vector_type(16)));
typedef unsigned short u16;
typedef unsigned int u32;

constexpr int LMAX = 8;

__device__ __forceinline__ u16 f2bf(float x) {
    u32 u = __float_as_uint(x);
    u += 0x7FFFu + ((u >> 16) & 1u);
    return (u16)(u >> 16);
}

__device__ __forceinline__ u32 cvt_pk_bf16(float lo, float hi) {
    u32 r;
    asm("v_cvt_pk_bf16_f32 %0, %1, %2" : "=v"(r) : "v"(lo), "v"(hi));
    return r;
}

__device__ __forceinline__ void pl32_swap(u32 &x, u32 &y) {
    asm volatile("v_permlane32_swap_b32 %0, %1" : "+v"(x), "+v"(y));
}

__device__ __forceinline__ bf16x8 frag_from(u32 a, u32 b, u32 c, u32 d) {
    union { u32 u[4]; bf16x8 v; } t;
    t.u[0] = a; t.u[1] = b; t.u[2] = c; t.u[3] = d;
    return t.v;
}

// ---------------- weight prepack (unchanged from round 3) ----------------
__global__ void prepack_kernel(const float* __restrict__ Ws1, const float* __restrict__ bs1,
                               const float* __restrict__ Ws2, const float* __restrict__ Wr1,
                               const float* __restrict__ br1, const float* __restrict__ Wr2,
                               u16* __restrict__ ws)
{
    int idx = blockIdx.x * blockDim.x + threadIdx.x;
    if (idx >= 36864) return;
    int e = idx & 511, l = e >> 3, j = e & 7, hi = l >> 5, l31 = l & 31;
    float val = 0.0f;
    if (idx < 12288) {
        int blk = idx >> 9;
        if (blk < 18) {
            int nt = blk / 3, kstep = blk % 3;
            int h = nt * 32 + l31;
            int k = kstep * 16 + 8 * hi + j;
            val = (k < 32) ? Wr1[k * 192 + h] : ((k == 32) ? br1[h] : 0.0f);
        } else {
            int h = (blk - 18) * 32 + l31;
            int k = 32 + 8 * hi + j;
            val = (k == 32) ? bs1[h] : ((k >= 33 && k <= 36) ? Ws1[(k - 33) * 192 + h] : 0.0f);
        }
    } else {
        int t = idx - 12288;
        int blk = t >> 9;
        int mlp = blk / 24, rem = blk % 24, ks = rem >> 1, nto = rem & 1;
        int k = 16 * ks + 8 * hi + j;
        int col = nto * 32 + l31;
        val = (mlp == 0 ? Wr2 : Ws2)[k * 64 + col];
    }
    ws[idx] = f2bf(val);
}

// ---------------- main fused kernel: 1 wave = 64 nodes ----------------
__global__ __launch_bounds__(256, 3) void node_embed_mfma(
    const float* __restrict__ v, const float* __restrict__ force,
    const int* __restrict__ is_moving, const float* __restrict__ rot_theta,
    const float* __restrict__ br2, const float* __restrict__ bs2,
    const u16* __restrict__ wpack,
    float* __restrict__ out, int n)
{
    __shared__ u16  Xs[4][64 * 40];   // per-wave X tile
    __shared__ float Os[4][8 * 72];   // per-wave output-transpose buffer (stride 72)

    const int lane = threadIdx.x & 63;
    const int w    = threadIdx.x >> 6;
    const int hi   = lane >> 5;
    const int l31  = lane & 31;
    const int rowl = lane >> 3;       // 0..7  (epilogue: node row within rq-group)
    const int ch   = lane & 7;        // 0..7  (epilogue: 8-float chunk)
    const int nodeBase = blockIdx.x * 256 + w * 64;

    // ---- featurization: lane = node ----
    const int node = nodeBase + lane;
    const int ldn  = min(node, n - 1);

    const float2 f2 = *reinterpret_cast<const float2*>(force + (size_t)ldn * 2);
    const float2 v2 = *reinterpret_cast<const float2*>(v     + (size_t)ldn * 2);
    const float fn = sqrtf(f2.x * f2.x + f2.y * f2.y);
    const float vn = sqrtf(v2.x * v2.x + v2.y * v2.y);
    const float cf = f2.x / fn, sf = f2.y / fn;
    const float cv = v2.x / vn, sv = v2.y / vn;
    const int mov = is_moving[ldn];

    float rotf[2 * LMAX], rotv[2 * LMAX];
    rotf[0] = cf; rotf[1] = sf;
    rotv[0] = cv; rotv[1] = sv;
    #pragma unroll
    for (int k = 1; k < LMAX; ++k) {
        rotf[2*k]   = rotf[2*k-2] * cf - rotf[2*k-1] * sf;
        rotf[2*k+1] = rotf[2*k-1] * cf + rotf[2*k-2] * sf;
        rotv[2*k]   = rotv[2*k-2] * cv - rotv[2*k-1] * sv;
        rotv[2*k+1] = rotv[2*k-1] * cv + rotv[2*k-2] * sv;
    }

    const float* Rbase = rot_theta + (size_t)ldn * 32;
    u16 xv[40];
    #pragma unroll
    for (int k = 0; k < LMAX; ++k) {
        const float4 R = *reinterpret_cast<const float4*>(Rbase + k * 4);
        {
            const float a = rotf[2*k], b = rotf[2*k+1];
            xv[2*k + 0] = f2bf(fmaf(R.x, a, R.y * b));
            xv[2*k + 1] = f2bf(fmaf(R.z, a, R.w * b));
        }
        {
            const float a = rotv[2*k], b = rotv[2*k+1];
            xv[16 + 2*k + 0] = f2bf(fmaf(R.x, a, R.y * b));
            xv[16 + 2*k + 1] = f2bf(fmaf(R.z, a, R.w * b));
        }
    }
    // cols 32..39: [1.0(bias), fn, vn, oh0, oh1, 0, 0, 0]
    xv[32] = 0x3F80;
    xv[33] = f2bf(fn);
    xv[34] = f2bf(vn);
    xv[35] = (mov == 0) ? 0x3F80 : 0;
    xv[36] = (mov == 1) ? 0x3F80 : 0;
    xv[37] = 0; xv[38] = 0; xv[39] = 0;

    {
        u32 xu[20];
        #pragma unroll
        for (int i = 0; i < 20; ++i)
            xu[i] = (u32)xv[2*i] | ((u32)xv[2*i+1] << 16);
        uint4* xdst = reinterpret_cast<uint4*>(&Xs[w][lane * 40]);
        #pragma unroll
        for (int i = 0; i < 5; ++i)
            xdst[i] = make_uint4(xu[4*i], xu[4*i+1], xu[4*i+2], xu[4*i+3]);
    }

    // per-lane output biases (col = nto*32 + l31)
    const float b2r0 = br2[l31], b2r1 = br2[32 + l31];
    const float b2s0 = bs2[l31], b2s1 = bs2[32 + l31];

    const u16* A1 = wpack;
    const u16* W2 = wpack + 12288;

    const int kbase = (ch & 1) * 4;   // epilogue rotation k-offset for this chunk

    for (int mg = 0; mg < 2; ++mg) {
        const int rowA = mg * 32 + l31;
        const bf16x8 xb0 = *reinterpret_cast<const bf16x8*>(&Xs[w][rowA * 40 + 8 * hi]);
        const bf16x8 xb1 = *reinterpret_cast<const bf16x8*>(&Xs[w][rowA * 40 + 16 + 8 * hi]);
        const bf16x8 xq4 = *reinterpret_cast<const bf16x8*>(&Xs[w][rowA * 40 + 32]);

        f32x16 acc0, acc1;

        // ===== rot MLP =====
        #pragma unroll
        for (int r = 0; r < 16; ++r) { acc0[r] = b2r0; acc1[r] = b2r1; }

        #pragma unroll
        for (int a = 0; a < 6; ++a) {
            f32x16 d1;
            #pragma unroll
            for (int r = 0; r < 16; ++r) d1[r] = 0.0f;
            d1 = __builtin_amdgcn_mfma_f32_32x32x16_bf16(
                *reinterpret_cast<const bf16x8*>(&A1[(a*3+0)*512 + lane*8]), xb0, d1, 0, 0, 0);
            d1 = __builtin_amdgcn_mfma_f32_32x32x16_bf16(
                *reinterpret_cast<const bf16x8*>(&A1[(a*3+1)*512 + lane*8]), xb1, d1, 0, 0, 0);
            d1 = __builtin_amdgcn_mfma_f32_32x32x16_bf16(
                *reinterpret_cast<const bf16x8*>(&A1[(a*3+2)*512 + lane*8]), xq4, d1, 0, 0, 0);

            u32 q[8];
            #pragma unroll
            for (int m = 0; m < 8; ++m)
                q[m] = cvt_pk_bf16(fmaxf(d1[2*m], 0.0f), fmaxf(d1[2*m+1], 0.0f));

            #pragma unroll
            for (int b = 0; b < 2; ++b) {
                u32 p0 = q[4*b + 0], p2 = q[4*b + 2];
                u32 p1 = q[4*b + 1], p3 = q[4*b + 3];
                pl32_swap(p0, p2);
                pl32_swap(p1, p3);
                const bf16x8 af = frag_from(p0, p1, p2, p3);
                const int ks = 2*a + b;
                acc0 = __builtin_amdgcn_mfma_f32_32x32x16_bf16(
                    af, *reinterpret_cast<const bf16x8*>(&W2[(ks*2+0)*512 + lane*8]), acc0, 0, 0, 0);
                acc1 = __builtin_amdgcn_mfma_f32_32x32x16_bf16(
                    af, *reinterpret_cast<const bf16x8*>(&W2[(ks*2+1)*512 + lane*8]), acc1, 0, 0, 0);
            }
        }

        // epilogue rot: LDS transpose -> in-lane rotation -> coalesced dwordx4
        #pragma unroll
        for (int rq = 0; rq < 4; ++rq) {
            #pragma unroll
            for (int rr = 0; rr < 4; ++rr) {
                const int r = rq * 4 + rr;
                Os[w][(rr + 4*hi) * 72 + l31]      = acc0[r];
                Os[w][(rr + 4*hi) * 72 + 32 + l31] = acc1[r];
            }
            const int node0 = nodeBase + mg * 32 + rq * 8 + rowl;
            const int ln0   = min(node0, n - 1);
            float4 o01 = *reinterpret_cast<const float4*>(&Os[w][rowl * 72 + 8 * ch]);
            float4 o23 = *reinterpret_cast<const float4*>(&Os[w][rowl * 72 + 8 * ch + 4]);
            const float* Rq = rot_theta + (size_t)ln0 * 32 + (size_t)kbase * 4;
            {
                const float4 R = *reinterpret_cast<const float4*>(Rq + 0);
                const float a = o01.x, b = o01.y;
                o01.x = fmaf(a, R.x, b * R.z); o01.y = fmaf(a, R.y, b * R.w);
            }
            {
                const float4 R = *reinterpret_cast<const float4*>(Rq + 4);
                const float a = o01.z, b = o01.w;
                o01.z = fmaf(a, R.x, b * R.z); o01.w = fmaf(a, R.y, b * R.w);
            }
            {
                const float4 R = *reinterpret_cast<const float4*>(Rq + 8);
                const float a = o23.x, b = o23.y;
                o23.x = fmaf(a, R.x, b * R.z); o23.y = fmaf(a, R.y, b * R.w);
            }
            {
                const float4 R = *reinterpret_cast<const float4*>(Rq + 12);
                const float a = o23.z, b = o23.w;
                o23.z = fmaf(a, R.x, b * R.z); o23.w = fmaf(a, R.y, b * R.w);
            }
            if (node0 < n) {
                float* dst = out + (size_t)n * 64 + (size_t)node0 * 64 + 8 * ch;
                *reinterpret_cast<float4*>(dst + 0) = o01;
                *reinterpret_cast<float4*>(dst + 4) = o23;
            }
        }

        // ===== scalar MLP =====
        #pragma unroll
        for (int r = 0; r < 16; ++r) { acc0[r] = b2s0; acc1[r] = b2s1; }

        #pragma unroll
        for (int a = 0; a < 6; ++a) {
            f32x16 d1;
            #pragma unroll
            for (int r = 0; r < 16; ++r) d1[r] = 0.0f;
            d1 = __builtin_amdgcn_mfma_f32_32x32x16_bf16(
                *reinterpret_cast<const bf16x8*>(&A1[(18 + a)*512 + lane*8]), xq4, d1, 0, 0, 0);

            u32 q[8];
            #pragma unroll
            for (int m = 0; m < 8; ++m)
                q[m] = cvt_pk_bf16(fmaxf(d1[2*m], 0.0f), fmaxf(d1[2*m+1], 0.0f));

            #pragma unroll
            for (int b = 0; b < 2; ++b) {
                u32 p0 = q[4*b + 0], p2 = q[4*b + 2];
                u32 p1 = q[4*b + 1], p3 = q[4*b + 3];
                pl32_swap(p0, p2);
                pl32_swap(p1, p3);
                const bf16x8 af = frag_from(p0, p1, p2, p3);
                const int ks = 2*a + b;
                acc0 = __builtin_amdgcn_mfma_f32_32x32x16_bf16(
                    af, *reinterpret_cast<const bf16x8*>(&W2[(24 + ks*2+0)*512 + lane*8]), acc0, 0, 0, 0);
                acc1 = __builtin_amdgcn_mfma_f32_32x32x16_bf16(
                    af, *reinterpret_cast<const bf16x8*>(&W2[(24 + ks*2+1)*512 + lane*8]), acc1, 0, 0, 0);
            }
        }

        // epilogue scalar: LDS transpose -> coalesced dwordx4 (no rotation)
        #pragma unroll
        for (int rq = 0; rq < 4; ++rq) {
            #pragma unroll
            for (int rr = 0; rr < 4; ++rr) {
                const int r = rq * 4 + rr;
                Os[w][(rr + 4*hi) * 72 + l31]      = acc0[r];
                Os[w][(rr + 4*hi) * 72 + 32 + l31] = acc1[r];
            }
            const int node0 = nodeBase + mg * 32 + rq * 8 + rowl;
            const float4 o01 = *reinterpret_cast<const float4*>(&Os[w][rowl * 72 + 8 * ch]);
            const float4 o23 = *reinterpret_cast<const float4*>(&Os[w][rowl * 72 + 8 * ch + 4]);
            if (node0 < n) {
                float* dst = out + (size_t)node0 * 64 + 8 * ch;
                *reinterpret_cast<float4*>(dst + 0) = o01;
                *reinterpret_cast<float4*>(dst + 4) = o23;
            }
        }
    }
}

// ---------------- fallback (VALU) if ws too small ----------------
__global__ __launch_bounds__(256) void node_embed_valu(
    const float* __restrict__ v, const float* __restrict__ force,
    const int* __restrict__ is_moving, const float* __restrict__ rot_theta,
    const float* __restrict__ Ws1, const float* __restrict__ bs1,
    const float* __restrict__ Ws2, const float* __restrict__ bs2,
    const float* __restrict__ Wr1, const float* __restrict__ br1,
    const float* __restrict__ Wr2, const float* __restrict__ br2,
    float* __restrict__ out, int n)
{
    const int node = blockIdx.x * blockDim.x + threadIdx.x;
    if (node >= n) return;
    const float2 f2 = *reinterpret_cast<const float2*>(force + (size_t)node * 2);
    const float2 v2 = *reinterpret_cast<const float2*>(v     + (size_t)node * 2);
    const float fn = sqrtf(f2.x * f2.x + f2.y * f2.y);
    const float vn = sqrtf(v2.x * v2.x + v2.y * v2.y);
    const float cf = f2.x / fn, sf = f2.y / fn;
    const float cv = v2.x / vn, sv = v2.y / vn;
    const int mov = is_moving[node];
    float rotf[16], rotv[16];
    rotf[0] = cf; rotf[1] = sf; rotv[0] = cv; rotv[1] = sv;
    #pragma unroll
    for (int k = 1; k < 8; ++k) {
        rotf[2*k]   = rotf[2*k-2] * cf - rotf[2*k-1] * sf;
        rotf[2*k+1] = rotf[2*k-1] * cf + rotf[2*k-2] * sf;
        rotv[2*k]   = rotv[2*k-2] * cv - rotv[2*k-1] * sv;
        rotv[2*k+1] = rotv[2*k-1] * cv + rotv[2*k-2] * sv;
    }
    const float* Rb = rot_theta + (size_t)node * 32;
    float x_in[32];
    #pragma unroll
    for (int k = 0; k < 8; ++k) {
        const float4 R = *reinterpret_cast<const float4*>(Rb + k * 4);
        { const float a = rotf[2*k], b = rotf[2*k+1];
          x_in[2*k] = fmaf(R.x,a,R.y*b); x_in[2*k+1] = fmaf(R.z,a,R.w*b); }
        { const float a = rotv[2*k], b = rotv[2*k+1];
          x_in[16+2*k] = fmaf(R.x,a,R.y*b); x_in[16+2*k+1] = fmaf(R.z,a,R.w*b); }
    }
    float acc[64];
    #pragma unroll
    for (int j = 0; j < 64; ++j) acc[j] = br2[j];
    for (int h = 0; h < 192; h += 4) {
        float hid[4];
        #pragma unroll
        for (int u = 0; u < 4; ++u) {
            float t = br1[h+u];
            #pragma unroll
            for (int i = 0; i < 32; ++i) t = fmaf(x_in[i], Wr1[i*192+h+u], t);
            hid[u] = fmaxf(t, 0.0f);
        }
        #pragma unroll
        for (int j = 0; j < 64; ++j) {
            float t = acc[j];
            #pragma unroll
            for (int u = 0; u < 4; ++u) t = fmaf(hid[u], Wr2[(h+u)*64+j], t);
            acc[j] = t;
        }
    }
    #pragma unroll
    for (int k = 0; k < 8; ++k) {
        const float4 R = *reinterpret_cast<const float4*>(Rb + k * 4);
        #pragma unroll
        for (int j = 0; j < 4; ++j) {
            const int p = j*16 + 2*k;
            const float a = acc[p], b = acc[p+1];
            acc[p] = fmaf(a,R.x,b*R.z); acc[p+1] = fmaf(a,R.y,b*R.w);
        }
    }
    float* orow = out + (size_t)n * 64 + (size_t)node * 64;
    #pragma unroll
    for (int j = 0; j < 16; ++j)
        *reinterpret_cast<float4*>(orow + 4*j) =
            make_float4(acc[4*j], acc[4*j+1], acc[4*j+2], acc[4*j+3]);
    const float s0 = fn, s1 = vn, s2 = (mov==0)?1.f:0.f, s3 = (mov==1)?1.f:0.f;
    #pragma unroll
    for (int j = 0; j < 64; ++j) acc[j] = bs2[j];
    for (int h = 0; h < 192; h += 4) {
        float hid[4];
        #pragma unroll
        for (int u = 0; u < 4; ++u) {
            float t = bs1[h+u];
            t = fmaf(s0, Ws1[0*192+h+u], t); t = fmaf(s1, Ws1[1*192+h+u], t);
            t = fmaf(s2, Ws1[2*192+h+u], t); t = fmaf(s3, Ws1[3*192+h+u], t);
            hid[u] = fmaxf(t, 0.0f);
        }
        #pragma unroll
        for (int j = 0; j < 64; ++j) {
            float t = acc[j];
            #pragma unroll
            for (int u = 0; u < 4; ++u) t = fmaf(hid[u], Ws2[(h+u)*64+j], t);
            acc[j] = t;
        }
    }
    orow = out + (size_t)node * 64;
    #pragma unroll
    for (int j = 0; j < 16; ++j)
        *reinterpret_cast<float4*>(orow + 4*j) =
            make_float4(acc[4*j], acc[4*j+1], acc[4*j+2], acc[4*j+3]);
}

extern "C" void kernel_launch(void* const* d_in, const int* in_sizes, int n_in,
                              void* d_out, int out_size, void* d_ws, size_t ws_size,
                              hipStream_t stream) {
    const int n = in_sizes[0] / 2;
    if (ws_size >= 36864 * sizeof(u16)) {
        hipLaunchKernelGGL(prepack_kernel, dim3(144), dim3(256), 0, stream,
                           (const float*)d_in[4],   // Ws1
                           (const float*)d_in[5],   // bs1
                           (const float*)d_in[6],   // Ws2
                           (const float*)d_in[8],   // Wr1
                           (const float*)d_in[9],   // br1
                           (const float*)d_in[10],  // Wr2
                           (u16*)d_ws);
        hipLaunchKernelGGL(node_embed_mfma, dim3((n + 255) / 256), dim3(256), 0, stream,
                           (const float*)d_in[0], (const float*)d_in[1],
                           (const int*)d_in[2],   (const float*)d_in[3],
                           (const float*)d_in[11],  // br2
                           (const float*)d_in[7],   // bs2
                           (const u16*)d_ws, (float*)d_out, n);
    } else {
        hipLaunchKernelGGL(node_embed_valu, dim3((n + 255) / 256), dim3(256), 0, stream,
                           (const float*)d_in[0], (const float*)d_in[1],
                           (const int*)d_in[2],   (const float*)d_in[3],
                           (const float*)d_in[4], (const float*)d_in[5],
                           (const float*)d_in[6], (const float*)d_in[7],
                           (const float*)d_in[8], (const float*)d_in[9],
                           (const float*)d_in[10],(const float*)d_in[11],
                           (float*)d_out, n);
    }
}

// Round 5
// 288.016 us; speedup vs baseline: 2.2988x; 1.7837x over previous
//
#include <hip/hip_runtime.h>
#include <math.h>

typedef short bf16x8 __attribute__((ext_vector_type(8)));
typedef float f32x16 __attribute__((ext_vector_type(16)));
typedef unsigned short u16;
typedef unsigned int u32;

constexpr int LMAX = 8;

__device__ __forceinline__ u16 f2bf(float x) {
    u32 u = __float_as_uint(x);
    u += 0x7FFFu + ((u >> 16) & 1u);
    return (u16)(u >> 16);
}

__device__ __forceinline__ u32 cvt_pk_bf16(float lo, float hi) {
    u32 r;
    asm("v_cvt_pk_bf16_f32 %0, %1, %2" : "=v"(r) : "v"(lo), "v"(hi));
    return r;
}

__device__ __forceinline__ void pl32_swap(u32 &x, u32 &y) {
    asm volatile("v_permlane32_swap_b32 %0, %1" : "+v"(x), "+v"(y));
}

__device__ __forceinline__ bf16x8 frag_from(u32 a, u32 b, u32 c, u32 d) {
    union { u32 u[4]; bf16x8 v; } t;
    t.u[0] = a; t.u[1] = b; t.u[2] = c; t.u[3] = d;
    return t.v;
}

// ---------------- weight prepack (unchanged) ----------------
__global__ void prepack_kernel(const float* __restrict__ Ws1, const float* __restrict__ bs1,
                               const float* __restrict__ Ws2, const float* __restrict__ Wr1,
                               const float* __restrict__ br1, const float* __restrict__ Wr2,
                               u16* __restrict__ ws)
{
    int idx = blockIdx.x * blockDim.x + threadIdx.x;
    if (idx >= 36864) return;
    int e = idx & 511, l = e >> 3, j = e & 7, hi = l >> 5, l31 = l & 31;
    float val = 0.0f;
    if (idx < 12288) {
        int blk = idx >> 9;
        if (blk < 18) {
            int nt = blk / 3, kstep = blk % 3;
            int h = nt * 32 + l31;
            int k = kstep * 16 + 8 * hi + j;
            val = (k < 32) ? Wr1[k * 192 + h] : ((k == 32) ? br1[h] : 0.0f);
        } else {
            int h = (blk - 18) * 32 + l31;
            int k = 32 + 8 * hi + j;
            val = (k == 32) ? bs1[h] : ((k >= 33 && k <= 36) ? Ws1[(k - 33) * 192 + h] : 0.0f);
        }
    } else {
        int t = idx - 12288;
        int blk = t >> 9;
        int mlp = blk / 24, rem = blk % 24, ks = rem >> 1, nto = rem & 1;
        int k = 16 * ks + 8 * hi + j;
        int col = nto * 32 + l31;
        val = (mlp == 0 ? Wr2 : Ws2)[k * 64 + col];
    }
    ws[idx] = f2bf(val);
}

// ---------------- main fused kernel: 1 wave = 64 nodes ----------------
__global__ __launch_bounds__(256, 3) void node_embed_mfma(
    const float* __restrict__ v, const float* __restrict__ force,
    const int* __restrict__ is_moving, const float* __restrict__ rot_theta,
    const float* __restrict__ br2, const float* __restrict__ bs2,
    const u16* __restrict__ wpack,
    float* __restrict__ out, int n)
{
    __shared__ u16   Xs[4][64 * 40];  // per-wave X tile
    __shared__ float Os[4][8 * 72];   // per-wave transpose buffer, stride 72 (16B-aligned rows)

    const int lane = threadIdx.x & 63;
    const int w    = threadIdx.x >> 6;
    const int hi   = lane >> 5;
    const int l31  = lane & 31;
    const int rowl = lane >> 4;       // 0..3  (epilogue: row within 4-row store group)
    const int qd   = lane & 15;       // 0..15 (epilogue: float4 chunk within 64-col row)
    const int nodeBase = blockIdx.x * 256 + w * 64;

    // ---- featurization: lane = node ----
    const int node = nodeBase + lane;
    const int ldn  = min(node, n - 1);

    const float2 f2 = *reinterpret_cast<const float2*>(force + (size_t)ldn * 2);
    const float2 v2 = *reinterpret_cast<const float2*>(v     + (size_t)ldn * 2);
    const float fn = sqrtf(f2.x * f2.x + f2.y * f2.y);
    const float vn = sqrtf(v2.x * v2.x + v2.y * v2.y);
    const float cf = f2.x / fn, sf = f2.y / fn;
    const float cv = v2.x / vn, sv = v2.y / vn;
    const int mov = is_moving[ldn];

    float rotf[2 * LMAX], rotv[2 * LMAX];
    rotf[0] = cf; rotf[1] = sf;
    rotv[0] = cv; rotv[1] = sv;
    #pragma unroll
    for (int k = 1; k < LMAX; ++k) {
        rotf[2*k]   = rotf[2*k-2] * cf - rotf[2*k-1] * sf;
        rotf[2*k+1] = rotf[2*k-1] * cf + rotf[2*k-2] * sf;
        rotv[2*k]   = rotv[2*k-2] * cv - rotv[2*k-1] * sv;
        rotv[2*k+1] = rotv[2*k-1] * cv + rotv[2*k-2] * sv;
    }

    const float* Rbase = rot_theta + (size_t)ldn * 32;
    u16 xv[40];
    #pragma unroll
    for (int k = 0; k < LMAX; ++k) {
        const float4 R = *reinterpret_cast<const float4*>(Rbase + k * 4);
        {
            const float a = rotf[2*k], b = rotf[2*k+1];
            xv[2*k + 0] = f2bf(fmaf(R.x, a, R.y * b));
            xv[2*k + 1] = f2bf(fmaf(R.z, a, R.w * b));
        }
        {
            const float a = rotv[2*k], b = rotv[2*k+1];
            xv[16 + 2*k + 0] = f2bf(fmaf(R.x, a, R.y * b));
            xv[16 + 2*k + 1] = f2bf(fmaf(R.z, a, R.w * b));
        }
    }
    // cols 32..39: [1.0(bias), fn, vn, oh0, oh1, 0, 0, 0]
    xv[32] = 0x3F80;
    xv[33] = f2bf(fn);
    xv[34] = f2bf(vn);
    xv[35] = (mov == 0) ? 0x3F80 : 0;
    xv[36] = (mov == 1) ? 0x3F80 : 0;
    xv[37] = 0; xv[38] = 0; xv[39] = 0;

    {
        u32 xu[20];
        #pragma unroll
        for (int i = 0; i < 20; ++i)
            xu[i] = (u32)xv[2*i] | ((u32)xv[2*i+1] << 16);
        uint4* xdst = reinterpret_cast<uint4*>(&Xs[w][lane * 40]);
        #pragma unroll
        for (int i = 0; i < 5; ++i)
            xdst[i] = make_uint4(xu[4*i], xu[4*i+1], xu[4*i+2], xu[4*i+3]);
    }

    // per-lane output biases (col = nto*32 + l31)
    const float b2r0 = br2[l31], b2r1 = br2[32 + l31];
    const float b2s0 = bs2[l31], b2s1 = bs2[32 + l31];

    const u16* A1 = wpack;
    const u16* W2 = wpack + 12288;

    for (int mg = 0; mg < 2; ++mg) {
        const int rowA = mg * 32 + l31;
        const bf16x8 xb0 = *reinterpret_cast<const bf16x8*>(&Xs[w][rowA * 40 + 8 * hi]);
        const bf16x8 xb1 = *reinterpret_cast<const bf16x8*>(&Xs[w][rowA * 40 + 16 + 8 * hi]);
        const bf16x8 xq4 = *reinterpret_cast<const bf16x8*>(&Xs[w][rowA * 40 + 32]);

        f32x16 acc0, acc1;

        // ===== rot MLP =====
        #pragma unroll
        for (int r = 0; r < 16; ++r) { acc0[r] = b2r0; acc1[r] = b2r1; }

        #pragma unroll
        for (int a = 0; a < 6; ++a) {
            f32x16 d1;
            #pragma unroll
            for (int r = 0; r < 16; ++r) d1[r] = 0.0f;
            d1 = __builtin_amdgcn_mfma_f32_32x32x16_bf16(
                *reinterpret_cast<const bf16x8*>(&A1[(a*3+0)*512 + lane*8]), xb0, d1, 0, 0, 0);
            d1 = __builtin_amdgcn_mfma_f32_32x32x16_bf16(
                *reinterpret_cast<const bf16x8*>(&A1[(a*3+1)*512 + lane*8]), xb1, d1, 0, 0, 0);
            d1 = __builtin_amdgcn_mfma_f32_32x32x16_bf16(
                *reinterpret_cast<const bf16x8*>(&A1[(a*3+2)*512 + lane*8]), xq4, d1, 0, 0, 0);

            u32 q[8];
            #pragma unroll
            for (int m = 0; m < 8; ++m)
                q[m] = cvt_pk_bf16(fmaxf(d1[2*m], 0.0f), fmaxf(d1[2*m+1], 0.0f));

            #pragma unroll
            for (int b = 0; b < 2; ++b) {
                u32 p0 = q[4*b + 0], p2 = q[4*b + 2];
                u32 p1 = q[4*b + 1], p3 = q[4*b + 3];
                pl32_swap(p0, p2);
                pl32_swap(p1, p3);
                const bf16x8 af = frag_from(p0, p1, p2, p3);
                const int ks = 2*a + b;
                acc0 = __builtin_amdgcn_mfma_f32_32x32x16_bf16(
                    af, *reinterpret_cast<const bf16x8*>(&W2[(ks*2+0)*512 + lane*8]), acc0, 0, 0, 0);
                acc1 = __builtin_amdgcn_mfma_f32_32x32x16_bf16(
                    af, *reinterpret_cast<const bf16x8*>(&W2[(ks*2+1)*512 + lane*8]), acc1, 0, 0, 0);
            }
        }

        // epilogue rot: LDS transpose -> in-lane rotation -> gap-free 1KB stores
        #pragma unroll
        for (int rq = 0; rq < 4; ++rq) {
            #pragma unroll
            for (int rr = 0; rr < 4; ++rr) {
                const int r = rq * 4 + rr;
                Os[w][(rr + 4*hi) * 72 + l31]      = acc0[r];
                Os[w][(rr + 4*hi) * 72 + 32 + l31] = acc1[r];
            }
            #pragma unroll
            for (int g = 0; g < 2; ++g) {
                const int row   = g * 4 + rowl;                       // 0..7
                const int node0 = nodeBase + mg * 32 + rq * 8 + row;
                const int ln0   = min(node0, n - 1);
                float4 o = *reinterpret_cast<const float4*>(&Os[w][row * 72 + 4 * qd]);
                const float* Rp = rot_theta + (size_t)ln0 * 32 + 8 * (qd & 3);
                const float4 Ra = *reinterpret_cast<const float4*>(Rp);
                const float4 Rb = *reinterpret_cast<const float4*>(Rp + 4);
                {
                    const float a = o.x, b = o.y;
                    o.x = fmaf(a, Ra.x, b * Ra.z); o.y = fmaf(a, Ra.y, b * Ra.w);
                }
                {
                    const float a = o.z, b = o.w;
                    o.z = fmaf(a, Rb.x, b * Rb.z); o.w = fmaf(a, Rb.y, b * Rb.w);
                }
                if (node0 < n) {
                    float* dst = out + (size_t)n * 64 + (size_t)node0 * 64 + 4 * qd;
                    *reinterpret_cast<float4*>(dst) = o;
                }
            }
        }

        // ===== scalar MLP =====
        #pragma unroll
        for (int r = 0; r < 16; ++r) { acc0[r] = b2s0; acc1[r] = b2s1; }

        #pragma unroll
        for (int a = 0; a < 6; ++a) {
            f32x16 d1;
            #pragma unroll
            for (int r = 0; r < 16; ++r) d1[r] = 0.0f;
            d1 = __builtin_amdgcn_mfma_f32_32x32x16_bf16(
                *reinterpret_cast<const bf16x8*>(&A1[(18 + a)*512 + lane*8]), xq4, d1, 0, 0, 0);

            u32 q[8];
            #pragma unroll
            for (int m = 0; m < 8; ++m)
                q[m] = cvt_pk_bf16(fmaxf(d1[2*m], 0.0f), fmaxf(d1[2*m+1], 0.0f));

            #pragma unroll
            for (int b = 0; b < 2; ++b) {
                u32 p0 = q[4*b + 0], p2 = q[4*b + 2];
                u32 p1 = q[4*b + 1], p3 = q[4*b + 3];
                pl32_swap(p0, p2);
                pl32_swap(p1, p3);
                const bf16x8 af = frag_from(p0, p1, p2, p3);
                const int ks = 2*a + b;
                acc0 = __builtin_amdgcn_mfma_f32_32x32x16_bf16(
                    af, *reinterpret_cast<const bf16x8*>(&W2[(24 + ks*2+0)*512 + lane*8]), acc0, 0, 0, 0);
                acc1 = __builtin_amdgcn_mfma_f32_32x32x16_bf16(
                    af, *reinterpret_cast<const bf16x8*>(&W2[(24 + ks*2+1)*512 + lane*8]), acc1, 0, 0, 0);
            }
        }

        // epilogue scalar: LDS transpose -> gap-free 1KB stores (no rotation)
        #pragma unroll
        for (int rq = 0; rq < 4; ++rq) {
            #pragma unroll
            for (int rr = 0; rr < 4; ++rr) {
                const int r = rq * 4 + rr;
                Os[w][(rr + 4*hi) * 72 + l31]      = acc0[r];
                Os[w][(rr + 4*hi) * 72 + 32 + l31] = acc1[r];
            }
            #pragma unroll
            for (int g = 0; g < 2; ++g) {
                const int row   = g * 4 + rowl;
                const int node0 = nodeBase + mg * 32 + rq * 8 + row;
                const float4 o = *reinterpret_cast<const float4*>(&Os[w][row * 72 + 4 * qd]);
                if (node0 < n) {
                    float* dst = out + (size_t)node0 * 64 + 4 * qd;
                    *reinterpret_cast<float4*>(dst) = o;
                }
            }
        }
    }
}

// ---------------- fallback (VALU) if ws too small ----------------
__global__ __launch_bounds__(256) void node_embed_valu(
    const float* __restrict__ v, const float* __restrict__ force,
    const int* __restrict__ is_moving, const float* __restrict__ rot_theta,
    const float* __restrict__ Ws1, const float* __restrict__ bs1,
    const float* __restrict__ Ws2, const float* __restrict__ bs2,
    const float* __restrict__ Wr1, const float* __restrict__ br1,
    const float* __restrict__ Wr2, const float* __restrict__ br2,
    float* __restrict__ out, int n)
{
    const int node = blockIdx.x * blockDim.x + threadIdx.x;
    if (node >= n) return;
    const float2 f2 = *reinterpret_cast<const float2*>(force + (size_t)node * 2);
    const float2 v2 = *reinterpret_cast<const float2*>(v     + (size_t)node * 2);
    const float fn = sqrtf(f2.x * f2.x + f2.y * f2.y);
    const float vn = sqrtf(v2.x * v2.x + v2.y * v2.y);
    const float cf = f2.x / fn, sf = f2.y / fn;
    const float cv = v2.x / vn, sv = v2.y / vn;
    const int mov = is_moving[node];
    float rotf[16], rotv[16];
    rotf[0] = cf; rotf[1] = sf; rotv[0] = cv; rotv[1] = sv;
    #pragma unroll
    for (int k = 1; k < 8; ++k) {
        rotf[2*k]   = rotf[2*k-2] * cf - rotf[2*k-1] * sf;
        rotf[2*k+1] = rotf[2*k-1] * cf + rotf[2*k-2] * sf;
        rotv[2*k]   = rotv[2*k-2] * cv - rotv[2*k-1] * sv;
        rotv[2*k+1] = rotv[2*k-1] * cv + rotv[2*k-2] * sv;
    }
    const float* Rb = rot_theta + (size_t)node * 32;
    float x_in[32];
    #pragma unroll
    for (int k = 0; k < 8; ++k) {
        const float4 R = *reinterpret_cast<const float4*>(Rb + k * 4);
        { const float a = rotf[2*k], b = rotf[2*k+1];
          x_in[2*k] = fmaf(R.x,a,R.y*b); x_in[2*k+1] = fmaf(R.z,a,R.w*b); }
        { const float a = rotv[2*k], b = rotv[2*k+1];
          x_in[16+2*k] = fmaf(R.x,a,R.y*b); x_in[16+2*k+1] = fmaf(R.z,a,R.w*b); }
    }
    float acc[64];
    #pragma unroll
    for (int j = 0; j < 64; ++j) acc[j] = br2[j];
    for (int h = 0; h < 192; h += 4) {
        float hid[4];
        #pragma unroll
        for (int u = 0; u < 4; ++u) {
            float t = br1[h+u];
            #pragma unroll
            for (int i = 0; i < 32; ++i) t = fmaf(x_in[i], Wr1[i*192+h+u], t);
            hid[u] = fmaxf(t, 0.0f);
        }
        #pragma unroll
        for (int j = 0; j < 64; ++j) {
            float t = acc[j];
            #pragma unroll
            for (int u = 0; u < 4; ++u) t = fmaf(hid[u], Wr2[(h+u)*64+j], t);
            acc[j] = t;
        }
    }
    #pragma unroll
    for (int k = 0; k < 8; ++k) {
        const float4 R = *reinterpret_cast<const float4*>(Rb + k * 4);
        #pragma unroll
        for (int j = 0; j < 4; ++j) {
            const int p = j*16 + 2*k;
            const float a = acc[p], b = acc[p+1];
            acc[p] = fmaf(a,R.x,b*R.z); acc[p+1] = fmaf(a,R.y,b*R.w);
        }
    }
    float* orow = out + (size_t)n * 64 + (size_t)node * 64;
    #pragma unroll
    for (int j = 0; j < 16; ++j)
        *reinterpret_cast<float4*>(orow + 4*j) =
            make_float4(acc[4*j], acc[4*j+1], acc[4*j+2], acc[4*j+3]);
    const float s0 = fn, s1 = vn, s2 = (mov==0)?1.f:0.f, s3 = (mov==1)?1.f:0.f;
    #pragma unroll
    for (int j = 0; j < 64; ++j) acc[j] = bs2[j];
    for (int h = 0; h < 192; h += 4) {
        float hid[4];
        #pragma unroll
        for (int u = 0; u < 4; ++u) {
            float t = bs1[h+u];
            t = fmaf(s0, Ws1[0*192+h+u], t); t = fmaf(s1, Ws1[1*192+h+u], t);
            t = fmaf(s2, Ws1[2*192+h+u], t); t = fmaf(s3, Ws1[3*192+h+u], t);
            hid[u] = fmaxf(t, 0.0f);
        }
        #pragma unroll
        for (int j = 0; j < 64; ++j) {
            float t = acc[j];
            #pragma unroll
            for (int u = 0; u < 4; ++u) t = fmaf(hid[u], Ws2[(h+u)*64+j], t);
            acc[j] = t;
        }
    }
    orow = out + (size_t)node * 64;
    #pragma unroll
    for (int j = 0; j < 16; ++j)
        *reinterpret_cast<float4*>(orow + 4*j) =
            make_float4(acc[4*j], acc[4*j+1], acc[4*j+2], acc[4*j+3]);
}

extern "C" void kernel_launch(void* const* d_in, const int* in_sizes, int n_in,
                              void* d_out, int out_size, void* d_ws, size_t ws_size,
                              hipStream_t stream) {
    const int n = in_sizes[0] / 2;
    if (ws_size >= 36864 * sizeof(u16)) {
        hipLaunchKernelGGL(prepack_kernel, dim3(144), dim3(256), 0, stream,
                           (const float*)d_in[4],   // Ws1
                           (const float*)d_in[5],   // bs1
                           (const float*)d_in[6],   // Ws2
                           (const float*)d_in[8],   // Wr1
                           (const float*)d_in[9],   // br1
                           (const float*)d_in[10],  // Wr2
                           (u16*)d_ws);
        hipLaunchKernelGGL(node_embed_mfma, dim3((n + 255) / 256), dim3(256), 0, stream,
                           (const float*)d_in[0], (const float*)d_in[1],
                           (const int*)d_in[2],   (const float*)d_in[3],
                           (const float*)d_in[11],  // br2
                           (const float*)d_in[7],   // bs2
                           (const u16*)d_ws, (float*)d_out, n);
    } else {
        hipLaunchKernelGGL(node_embed_valu, dim3((n + 255) / 256), dim3(256), 0, stream,
                           (const float*)d_in[0], (const float*)d_in[1],
                           (const int*)d_in[2],   (const float*)d_in[3],
                           (const float*)d_in[4], (const float*)d_in[5],
                           (const float*)d_in[6], (const float*)d_in[7],
                           (const float*)d_in[8], (const float*)d_in[9],
                           (const float*)d_in[10],(const float*)d_in[11],
                           (float*)d_out, n);
    }
}